// Round 1
// baseline (1097.488 us; speedup 1.0000x reference)
//
#include <hip/hip_runtime.h>

// HybridGeometryFeatures: B=2, N=12288, K=16 nearest neighbors (excl self),
// per-point covariance eigen features.
// ws layout: [0, 393216): float4 packed points; then 6.29 MB u16 partial knn idx.
// Total ws needed ~6.7 MB.

#define NPTS 12288
#define NBATCH 2
#define KNN 16
#define NCHUNK 8
#define CHUNKSZ (NPTS / NCHUNK) // 1536

typedef unsigned long long u64;
typedef unsigned short u16;

__global__ __launch_bounds__(256) void pack_kernel(const float* __restrict__ xyz,
                                                   float4* __restrict__ pts4) {
  int i = blockIdx.x * 256 + threadIdx.x;
  if (i < NBATCH * NPTS) {
    pts4[i] = make_float4(xyz[3 * i + 0], xyz[3 * i + 1], xyz[3 * i + 2], 0.0f);
  }
}

// One thread = one query point x one candidate chunk. Keeps top-16 as sorted
// u64 keys (distbits<<32 | idx), best[0] = worst. Writes 16 u16 indices.
__global__ __launch_bounds__(256) void knn_chunk_kernel(const float4* __restrict__ pts4,
                                                        u16* __restrict__ pidx) {
  int bid = blockIdx.x;
  int chunk = bid & (NCHUNK - 1);
  int rest = bid >> 3;
  int qblk = rest % (NPTS / 256);
  int b = rest / (NPTS / 256);
  int q = qblk * 256 + threadIdx.x;
  const float4* P = pts4 + (size_t)b * NPTS;

  __shared__ float4 cpts[CHUNKSZ]; // 24 KB
  int cbase = chunk * CHUNKSZ;
  for (int i = threadIdx.x; i < CHUNKSZ; i += 256) cpts[i] = P[cbase + i];
  __syncthreads();

  float4 Q = P[q];
  u64 best[KNN];
#pragma unroll
  for (int j = 0; j < KNN; ++j) best[j] = ~0ULL;

  for (int c = 0; c < CHUNKSZ; ++c) {
    float4 pp = cpts[c];
    float dx = Q.x - pp.x, dy = Q.y - pp.y, dz = Q.z - pp.z;
    float d2 = fmaf(dz, dz, fmaf(dy, dy, dx * dx));
    int ci = cbase + c;
    u64 key = ((u64)__float_as_uint(d2) << 32) | (unsigned)ci;
    if (ci == q) key = ~0ULL; // exclude self
    if (key < best[0]) {
      best[0] = key;
#pragma unroll
      for (int j = 0; j < KNN - 1; ++j) { // one bubble pass restores sorted desc
        u64 a = best[j], bb = best[j + 1];
        u64 mx = a > bb ? a : bb;
        u64 mn = a > bb ? bb : a;
        best[j] = mx;
        best[j + 1] = mn;
      }
    }
  }
  u16* o = pidx + ((((size_t)b * NPTS + q) * NCHUNK) + chunk) * KNN;
#pragma unroll
  for (int j = 0; j < KNN; ++j) o[j] = (u16)(best[KNN - 1 - j] & 0xFFFFu);
}

// Merge 8 partial lists -> true top-16 (distances recomputed bit-identically),
// then centroid/cov (f32) + analytic 3x3 eigensolve (f64) + features.
__global__ __launch_bounds__(64) void feat_kernel(const float4* __restrict__ pts4,
                                                  const float* __restrict__ normals,
                                                  const u16* __restrict__ pidx,
                                                  float* __restrict__ out) {
  int t = blockIdx.x * 64 + threadIdx.x; // 0 .. B*N-1
  int b = t / NPTS;
  int q = t - b * NPTS;
  const float4* P = pts4 + (size_t)b * NPTS;
  float4 Q = P[q];

  u64 best[KNN];
#pragma unroll
  for (int j = 0; j < KNN; ++j) best[j] = ~0ULL;

  const u16* pp = pidx + (size_t)t * (NCHUNK * KNN);
  for (int m = 0; m < NCHUNK * KNN; ++m) {
    int ci = pp[m];
    float4 c4 = P[ci];
    float dx = Q.x - c4.x, dy = Q.y - c4.y, dz = Q.z - c4.z;
    float d2 = fmaf(dz, dz, fmaf(dy, dy, dx * dx));
    u64 key = ((u64)__float_as_uint(d2) << 32) | (unsigned)ci;
    if (key < best[0]) {
      best[0] = key;
#pragma unroll
      for (int j = 0; j < KNN - 1; ++j) {
        u64 a = best[j], bb = best[j + 1];
        u64 mx = a > bb ? a : bb;
        u64 mn = a > bb ? bb : a;
        best[j] = mx;
        best[j + 1] = mn;
      }
    }
  }

  // Gather neighbors into registers (static indexing only).
  float nx[KNN], ny[KNN], nz[KNN];
  float sx = 0.f, sy = 0.f, sz = 0.f;
#pragma unroll
  for (int j = 0; j < KNN; ++j) {
    int ci = (int)(best[j] & 0xFFFFFFFFu);
    float4 c4 = P[ci];
    nx[j] = c4.x; ny[j] = c4.y; nz[j] = c4.z;
    sx += c4.x; sy += c4.y; sz += c4.z;
  }
  const float invK = 1.0f / 16.0f;
  float cx = sx * invK, cy = sy * invK, cz = sz * invK;

  float c00 = 0.f, c01 = 0.f, c02 = 0.f, c11 = 0.f, c12 = 0.f, c22 = 0.f;
#pragma unroll
  for (int j = 0; j < KNN; ++j) {
    float dx = nx[j] - cx, dy = ny[j] - cy, dz = nz[j] - cz;
    c00 += dx * dx; c01 += dx * dy; c02 += dx * dz;
    c11 += dy * dy; c12 += dy * dz; c22 += dz * dz;
  }
  const float inv15 = 1.0f / 15.0f;
  c00 *= inv15; c01 *= inv15; c02 *= inv15;
  c11 *= inv15; c12 *= inv15; c22 *= inv15;

  // f64 analytic eigensolve (trig method) for smallest eigenvalue.
  double a00 = c00, a01 = c01, a02 = c02, a11 = c11, a12 = c12, a22 = c22;
  double tr = a00 + a11 + a22;
  double qm = tr * (1.0 / 3.0);
  double p1 = a01 * a01 + a02 * a02 + a12 * a12;
  double b00 = a00 - qm, b11 = a11 - qm, b22 = a22 - qm;
  double p2 = b00 * b00 + b11 * b11 + b22 * b22 + 2.0 * p1;
  double lmin = qm;
  if (p2 > 0.0) {
    double p = sqrt(p2 * (1.0 / 6.0));
    double ip = 1.0 / p;
    double q00 = b00 * ip, q01 = a01 * ip, q02 = a02 * ip;
    double q11 = b11 * ip, q12 = a12 * ip, q22 = b22 * ip;
    double det = q00 * (q11 * q22 - q12 * q12) - q01 * (q01 * q22 - q12 * q02) +
                 q02 * (q01 * q12 - q11 * q02);
    double r = 0.5 * det;
    r = r < -1.0 ? -1.0 : (r > 1.0 ? 1.0 : r);
    double phi = acos(r) * (1.0 / 3.0);
    lmin = qm + 2.0 * p * cos(phi + 2.0943951023931953); // 2*pi/3 -> smallest
  }

  // Eigenvector for lmin: cross products of rows of (A - lmin I); pick largest.
  double m00 = a00 - lmin, m11 = a11 - lmin, m22 = a22 - lmin;
  double v0x = a01 * a12 - a02 * m11;
  double v0y = a02 * a01 - m00 * a12;
  double v0z = m00 * m11 - a01 * a01;
  double v1x = a01 * m22 - a02 * a12;
  double v1y = a02 * a02 - m00 * m22;
  double v1z = m00 * a12 - a01 * a02;
  double v2x = m11 * m22 - a12 * a12;
  double v2y = a12 * a02 - a01 * m22;
  double v2z = a01 * a12 - m11 * a02;
  double n0 = v0x * v0x + v0y * v0y + v0z * v0z;
  double n1 = v1x * v1x + v1y * v1y + v1z * v1z;
  double n2 = v2x * v2x + v2y * v2y + v2z * v2z;
  double vx, vy, vz, nn;
  if (n0 >= n1 && n0 >= n2) { vx = v0x; vy = v0y; vz = v0z; nn = n0; }
  else if (n1 >= n2)        { vx = v1x; vy = v1y; vz = v1z; nn = n1; }
  else                      { vx = v2x; vy = v2y; vz = v2z; nn = n2; }
  if (nn < 1e-60) { vx = 0.0; vy = 0.0; vz = 1.0; nn = 1.0; }
  double inn = 1.0 / sqrt(nn);
  vx *= inn; vy *= inn; vz *= inn;

  float nrx = normals[3 * (size_t)t + 0];
  float nry = normals[3 * (size_t)t + 1];
  float nrz = normals[3 * (size_t)t + 2];
  double dot = vx * (double)nrx + vy * (double)nry + vz * (double)nrz;
  float cons = (float)fabs(dot);

  float vxf = (float)vx, vyf = (float)vy, vzf = (float)vz;
  float s = 0.f;
#pragma unroll
  for (int j = 0; j < KNN; ++j) {
    s += fabsf((nx[j] - cx) * vxf + (ny[j] - cy) * vyf + (nz[j] - cz) * vzf);
  }
  float rough = s * invK;

  float trf = c00 + c11 + c22;
  float curv = (float)lmin / fmaxf(trf, 1e-8f);

  float* o = out + (size_t)t * 6;
  o[0] = cons;
  o[1] = nrx;
  o[2] = nry;
  o[3] = nrz;
  o[4] = curv;
  o[5] = rough;
}

extern "C" void kernel_launch(void* const* d_in, const int* in_sizes, int n_in,
                              void* d_out, int out_size, void* d_ws, size_t ws_size,
                              hipStream_t stream) {
  const float* xyz = (const float*)d_in[0];
  const float* normals = (const float*)d_in[1];
  float* out = (float*)d_out;

  float4* pts4 = (float4*)d_ws;
  u16* pidx = (u16*)((char*)d_ws + (size_t)NBATCH * NPTS * sizeof(float4));

  pack_kernel<<<(NBATCH * NPTS + 255) / 256, 256, 0, stream>>>(xyz, pts4);
  knn_chunk_kernel<<<NBATCH * (NPTS / 256) * NCHUNK, 256, 0, stream>>>(pts4, pidx);
  feat_kernel<<<(NBATCH * NPTS) / 64, 64, 0, stream>>>(pts4, normals, pidx, out);
}

// Round 2
// 249.453 us; speedup vs baseline: 4.3996x; 4.3996x over previous
//
#include <hip/hip_runtime.h>

// HybridGeometryFeatures: B=2, N=12288, K=16 NN (excl self) + covariance eig features.
// Pipeline: pack(SoA) -> knn_dist (branchless per-chunk top-8 distances)
//        -> thresh (t_q = 16th smallest of union)  -> collect (indices with d2<=t_q)
//        -> feat (exact top-16 re-select + eigensolve).
// ws: xs/ys/zs (0.3MB) | cdist [NQ][16][8] f32 (12.6MB, reused as cidx u16) |
//     tq (0.1MB) | ccnt (1.6MB). Total ~14.6MB.

#define NPTS 12288
#define NBATCH 2
#define NQ (NPTS * NBATCH)
#define KNN 16
#define NCH 16
#define CHSZ (NPTS / NCH) // 768
#define MKEEP 8
#define CAP 16
#define QBLK (NQ / 256) // 96

typedef unsigned long long u64;
typedef unsigned short u16;
typedef unsigned int u32;

#define FINF __builtin_inff()
#define SWAPF(a, b) { float _lo = fminf(a, b); float _hi = fmaxf(a, b); a = _lo; b = _hi; }
#define DIST(dst, px, py, pz) { float _dx = Qx - (px); float _dy = Qy - (py); float _dz = Qz - (pz); \
                                dst = fmaf(_dz, _dz, fmaf(_dy, _dy, _dx * _dx)); }

__global__ __launch_bounds__(256) void pack_kernel(const float* __restrict__ xyz,
                                                   float* __restrict__ xs,
                                                   float* __restrict__ ys,
                                                   float* __restrict__ zs) {
  int i = blockIdx.x * 256 + threadIdx.x;
  if (i < NQ) {
    xs[i] = xyz[3 * i + 0];
    ys[i] = xyz[3 * i + 1];
    zs[i] = xyz[3 * i + 2];
  }
}

// K2: per (query, chunk) branchless top-8 distances.
__global__ __launch_bounds__(256) void knn_dist_kernel(const float* __restrict__ xs,
                                                       const float* __restrict__ ys,
                                                       const float* __restrict__ zs,
                                                       float* __restrict__ cdist) {
  int bid = blockIdx.x;
  int qb = bid % QBLK;
  int ch = bid / QBLK;
  int q = qb * 256 + threadIdx.x;
  int b = q / NPTS; // uniform per block (NPTS % 256 == 0)
  int base = b * NPTS + ch * CHSZ;

  __shared__ __align__(16) float lx[CHSZ];
  __shared__ __align__(16) float ly[CHSZ];
  __shared__ __align__(16) float lz[CHSZ];
  {
    float4* sx = (float4*)lx; float4* sy = (float4*)ly; float4* sz = (float4*)lz;
    const float4* gx = (const float4*)(xs + base);
    const float4* gy = (const float4*)(ys + base);
    const float4* gz = (const float4*)(zs + base);
    for (int i = threadIdx.x; i < CHSZ / 4; i += 256) { sx[i] = gx[i]; sy[i] = gy[i]; sz[i] = gz[i]; }
  }
  __syncthreads();

  float Qx = xs[q], Qy = ys[q], Qz = zs[q];
  int qrel = q - base; // in [0,CHSZ) only if self in this chunk

  float r0 = FINF, r1 = FINF, r2 = FINF, r3 = FINF, r4 = FINF, r5 = FINF, r6 = FINF, r7 = FINF;
  const float4* lx4 = (const float4*)lx;
  const float4* ly4 = (const float4*)ly;
  const float4* lz4 = (const float4*)lz;

#pragma unroll 1
  for (int c0 = 0; c0 < CHSZ; c0 += 8) {
    float4 xA = lx4[c0 / 4], xB = lx4[c0 / 4 + 1];
    float4 yA = ly4[c0 / 4], yB = ly4[c0 / 4 + 1];
    float4 zA = lz4[c0 / 4], zB = lz4[c0 / 4 + 1];
    float d0, d1, d2_, d3, d4, d5, d6, d7;
    DIST(d0, xA.x, yA.x, zA.x); DIST(d1, xA.y, yA.y, zA.y);
    DIST(d2_, xA.z, yA.z, zA.z); DIST(d3, xA.w, yA.w, zA.w);
    DIST(d4, xB.x, yB.x, zB.x); DIST(d5, xB.y, yB.y, zB.y);
    DIST(d6, xB.z, yB.z, zB.z); DIST(d7, xB.w, yB.w, zB.w);
    int rel = qrel - c0;
    d0 = (rel == 0) ? FINF : d0; d1 = (rel == 1) ? FINF : d1;
    d2_ = (rel == 2) ? FINF : d2_; d3 = (rel == 3) ? FINF : d3;
    d4 = (rel == 4) ? FINF : d4; d5 = (rel == 5) ? FINF : d5;
    d6 = (rel == 6) ? FINF : d6; d7 = (rel == 7) ? FINF : d7;
    // Batcher sort-8 ascending (19 CEs)
    SWAPF(d0, d1) SWAPF(d2_, d3) SWAPF(d4, d5) SWAPF(d6, d7)
    SWAPF(d0, d2_) SWAPF(d1, d3) SWAPF(d4, d6) SWAPF(d5, d7)
    SWAPF(d1, d2_) SWAPF(d5, d6)
    SWAPF(d0, d4) SWAPF(d1, d5) SWAPF(d2_, d6) SWAPF(d3, d7)
    SWAPF(d2_, d4) SWAPF(d3, d5)
    SWAPF(d1, d2_) SWAPF(d3, d4) SWAPF(d5, d6)
    // merge: lowest-8 of (run, batch) -> bitonic -> resort (12 CEs)
    float m0 = fminf(r0, d7), m1 = fminf(r1, d6), m2 = fminf(r2, d5), m3 = fminf(r3, d4);
    float m4 = fminf(r4, d3), m5 = fminf(r5, d2_), m6 = fminf(r6, d1), m7 = fminf(r7, d0);
    SWAPF(m0, m4) SWAPF(m1, m5) SWAPF(m2, m6) SWAPF(m3, m7)
    SWAPF(m0, m2) SWAPF(m1, m3) SWAPF(m4, m6) SWAPF(m5, m7)
    SWAPF(m0, m1) SWAPF(m2, m3) SWAPF(m4, m5) SWAPF(m6, m7)
    r0 = m0; r1 = m1; r2 = m2; r3 = m3; r4 = m4; r5 = m5; r6 = m6; r7 = m7;
  }
  float4* o = (float4*)(cdist + ((size_t)q * NCH + ch) * MKEEP);
  o[0] = make_float4(r0, r1, r2, r3);
  o[1] = make_float4(r4, r5, r6, r7);
}

// K2.5: t_q = 16th smallest of the 128 per-chunk values (>= true 16NN dist).
__global__ __launch_bounds__(64) void thresh_kernel(const float* __restrict__ cdist,
                                                    float* __restrict__ tq) {
  __shared__ float v[64 * 129]; // row stride 129 (odd) -> conflict-free scans
  int tid = threadIdx.x;
  size_t base = (size_t)blockIdx.x * 64 * 128;
  for (int r = 0; r < 64; ++r) {
    v[r * 129 + tid] = cdist[base + r * 128 + tid];
    v[r * 129 + 64 + tid] = cdist[base + r * 128 + 64 + tid];
  }
  __syncthreads();
  float* row = v + tid * 129;
  float last = 0.f;
  for (int k = 0; k < KNN; ++k) {
    float mv = FINF; int mi = 0;
    for (int i = 0; i < 128; ++i) {
      float x = row[i];
      if (x < mv) { mv = x; mi = i; }
    }
    row[mi] = FINF;
    last = mv;
  }
  tq[blockIdx.x * 64 + tid] = last;
}

// K3: collect candidate indices with d2 <= t_q (bit-identical distance expr).
__global__ __launch_bounds__(256) void collect_kernel(const float* __restrict__ xs,
                                                      const float* __restrict__ ys,
                                                      const float* __restrict__ zs,
                                                      const float* __restrict__ tq,
                                                      u16* __restrict__ cidx,
                                                      u32* __restrict__ ccnt) {
  int bid = blockIdx.x;
  int qb = bid % QBLK;
  int ch = bid / QBLK;
  int q = qb * 256 + threadIdx.x;
  int b = q / NPTS;
  int base = b * NPTS + ch * CHSZ;

  __shared__ __align__(16) float lx[CHSZ];
  __shared__ __align__(16) float ly[CHSZ];
  __shared__ __align__(16) float lz[CHSZ];
  {
    float4* sx = (float4*)lx; float4* sy = (float4*)ly; float4* sz = (float4*)lz;
    const float4* gx = (const float4*)(xs + base);
    const float4* gy = (const float4*)(ys + base);
    const float4* gz = (const float4*)(zs + base);
    for (int i = threadIdx.x; i < CHSZ / 4; i += 256) { sx[i] = gx[i]; sy[i] = gy[i]; sz[i] = gz[i]; }
  }
  __syncthreads();

  float Qx = xs[q], Qy = ys[q], Qz = zs[q];
  float t = tq[q];
  int qrel = q - base;
  int cnt = 0;
  u16* o = cidx + ((size_t)q * NCH + ch) * CAP;
  const float4* lx4 = (const float4*)lx;
  const float4* ly4 = (const float4*)ly;
  const float4* lz4 = (const float4*)lz;

#pragma unroll 1
  for (int c0 = 0; c0 < CHSZ; c0 += 4) {
    float4 cx = lx4[c0 / 4], cy = ly4[c0 / 4], cz = lz4[c0 / 4];
    float e0, e1, e2, e3;
    DIST(e0, cx.x, cy.x, cz.x); DIST(e1, cx.y, cy.y, cz.y);
    DIST(e2, cx.z, cy.z, cz.z); DIST(e3, cx.w, cy.w, cz.w);
    if (e0 <= t && (c0 + 0) != qrel && cnt < CAP) { o[cnt] = (u16)(ch * CHSZ + c0 + 0); ++cnt; }
    if (e1 <= t && (c0 + 1) != qrel && cnt < CAP) { o[cnt] = (u16)(ch * CHSZ + c0 + 1); ++cnt; }
    if (e2 <= t && (c0 + 2) != qrel && cnt < CAP) { o[cnt] = (u16)(ch * CHSZ + c0 + 2); ++cnt; }
    if (e3 <= t && (c0 + 3) != qrel && cnt < CAP) { o[cnt] = (u16)(ch * CHSZ + c0 + 3); ++cnt; }
  }
  ccnt[(size_t)q * NCH + ch] = (u32)cnt;
}

// K4: exact top-16 among collected + covariance/eigen features.
__global__ __launch_bounds__(64) void feat_kernel(const float* __restrict__ xs,
                                                  const float* __restrict__ ys,
                                                  const float* __restrict__ zs,
                                                  const float* __restrict__ normals,
                                                  const u16* __restrict__ cidx,
                                                  const u32* __restrict__ ccnt,
                                                  float* __restrict__ out) {
  int t = blockIdx.x * 64 + threadIdx.x;
  int b = t / NPTS;
  int bbase = b * NPTS;
  float Qx = xs[t], Qy = ys[t], Qz = zs[t];

  u64 best[KNN];
#pragma unroll
  for (int j = 0; j < KNN; ++j) best[j] = ~0ULL;

  for (int ch = 0; ch < NCH; ++ch) {
    int n = (int)ccnt[(size_t)t * NCH + ch];
    n = n < CAP ? n : CAP;
    const u16* ix = cidx + ((size_t)t * NCH + ch) * CAP;
    for (int j = 0; j < n; ++j) {
      int ci = ix[j];
      float d2;
      DIST(d2, xs[bbase + ci], ys[bbase + ci], zs[bbase + ci]);
      u64 key = ((u64)__float_as_uint(d2) << 32) | (u32)ci;
      if (key < best[0]) {
        best[0] = key;
#pragma unroll
        for (int jj = 0; jj < KNN - 1; ++jj) {
          u64 a = best[jj], bb = best[jj + 1];
          u64 mx = a > bb ? a : bb;
          u64 mn = a > bb ? bb : a;
          best[jj] = mx;
          best[jj + 1] = mn;
        }
      }
    }
  }

  float nx[KNN], ny[KNN], nz[KNN];
  float sx = 0.f, sy = 0.f, sz = 0.f;
#pragma unroll
  for (int j = 0; j < KNN; ++j) {
    int ci = (int)(best[j] & 0xFFFFFFFFu);
    if (ci >= NPTS) ci = 0; // safety (never expected)
    float px = xs[bbase + ci], py = ys[bbase + ci], pz = zs[bbase + ci];
    nx[j] = px; ny[j] = py; nz[j] = pz;
    sx += px; sy += py; sz += pz;
  }
  const float invK = 1.0f / 16.0f;
  float cx = sx * invK, cy = sy * invK, cz = sz * invK;

  float c00 = 0.f, c01 = 0.f, c02 = 0.f, c11 = 0.f, c12 = 0.f, c22 = 0.f;
#pragma unroll
  for (int j = 0; j < KNN; ++j) {
    float dx = nx[j] - cx, dy = ny[j] - cy, dz = nz[j] - cz;
    c00 += dx * dx; c01 += dx * dy; c02 += dx * dz;
    c11 += dy * dy; c12 += dy * dz; c22 += dz * dz;
  }
  const float inv15 = 1.0f / 15.0f;
  c00 *= inv15; c01 *= inv15; c02 *= inv15;
  c11 *= inv15; c12 *= inv15; c22 *= inv15;

  double a00 = c00, a01 = c01, a02 = c02, a11 = c11, a12 = c12, a22 = c22;
  double tr = a00 + a11 + a22;
  double qm = tr * (1.0 / 3.0);
  double p1 = a01 * a01 + a02 * a02 + a12 * a12;
  double b00 = a00 - qm, b11 = a11 - qm, b22 = a22 - qm;
  double p2 = b00 * b00 + b11 * b11 + b22 * b22 + 2.0 * p1;
  double lmin = qm;
  if (p2 > 0.0) {
    double p = sqrt(p2 * (1.0 / 6.0));
    double ip = 1.0 / p;
    double q00 = b00 * ip, q01 = a01 * ip, q02 = a02 * ip;
    double q11 = b11 * ip, q12 = a12 * ip, q22 = b22 * ip;
    double det = q00 * (q11 * q22 - q12 * q12) - q01 * (q01 * q22 - q12 * q02) +
                 q02 * (q01 * q12 - q11 * q02);
    double r = 0.5 * det;
    r = r < -1.0 ? -1.0 : (r > 1.0 ? 1.0 : r);
    double phi = acos(r) * (1.0 / 3.0);
    lmin = qm + 2.0 * p * cos(phi + 2.0943951023931953);
  }

  double m00 = a00 - lmin, m11 = a11 - lmin, m22 = a22 - lmin;
  double v0x = a01 * a12 - a02 * m11;
  double v0y = a02 * a01 - m00 * a12;
  double v0z = m00 * m11 - a01 * a01;
  double v1x = a01 * m22 - a02 * a12;
  double v1y = a02 * a02 - m00 * m22;
  double v1z = m00 * a12 - a01 * a02;
  double v2x = m11 * m22 - a12 * a12;
  double v2y = a12 * a02 - a01 * m22;
  double v2z = a01 * a12 - m11 * a02;
  double n0 = v0x * v0x + v0y * v0y + v0z * v0z;
  double n1 = v1x * v1x + v1y * v1y + v1z * v1z;
  double n2 = v2x * v2x + v2y * v2y + v2z * v2z;
  double vx, vy, vz, nn;
  if (n0 >= n1 && n0 >= n2) { vx = v0x; vy = v0y; vz = v0z; nn = n0; }
  else if (n1 >= n2)        { vx = v1x; vy = v1y; vz = v1z; nn = n1; }
  else                      { vx = v2x; vy = v2y; vz = v2z; nn = n2; }
  if (nn < 1e-60) { vx = 0.0; vy = 0.0; vz = 1.0; nn = 1.0; }
  double inn = 1.0 / sqrt(nn);
  vx *= inn; vy *= inn; vz *= inn;

  float nrx = normals[3 * (size_t)t + 0];
  float nry = normals[3 * (size_t)t + 1];
  float nrz = normals[3 * (size_t)t + 2];
  double dot = vx * (double)nrx + vy * (double)nry + vz * (double)nrz;
  float cons = (float)fabs(dot);

  float vxf = (float)vx, vyf = (float)vy, vzf = (float)vz;
  float s = 0.f;
#pragma unroll
  for (int j = 0; j < KNN; ++j) {
    s += fabsf((nx[j] - cx) * vxf + (ny[j] - cy) * vyf + (nz[j] - cz) * vzf);
  }
  float rough = s * invK;

  float trf = c00 + c11 + c22;
  float curv = (float)lmin / fmaxf(trf, 1e-8f);

  float* o = out + (size_t)t * 6;
  o[0] = cons;
  o[1] = nrx;
  o[2] = nry;
  o[3] = nrz;
  o[4] = curv;
  o[5] = rough;
}

extern "C" void kernel_launch(void* const* d_in, const int* in_sizes, int n_in,
                              void* d_out, int out_size, void* d_ws, size_t ws_size,
                              hipStream_t stream) {
  const float* xyz = (const float*)d_in[0];
  const float* normals = (const float*)d_in[1];
  float* out = (float*)d_out;

  float* xs = (float*)d_ws;
  float* ys = xs + NQ;
  float* zs = ys + NQ;
  float* cdist = zs + NQ;                       // NQ*128 floats
  float* tq = cdist + (size_t)NQ * NCH * MKEEP; // NQ floats
  u32* ccnt = (u32*)(tq + NQ);                  // NQ*NCH u32
  u16* cidx = (u16*)cdist;                      // overlap reuse (K2.5 consumed cdist)

  pack_kernel<<<NQ / 256, 256, 0, stream>>>(xyz, xs, ys, zs);
  knn_dist_kernel<<<QBLK * NCH, 256, 0, stream>>>(xs, ys, zs, cdist);
  thresh_kernel<<<NQ / 64, 64, 0, stream>>>(cdist, tq);
  collect_kernel<<<QBLK * NCH, 256, 0, stream>>>(xs, ys, zs, tq, cidx, ccnt);
  feat_kernel<<<NQ / 64, 64, 0, stream>>>(xs, ys, zs, normals, cidx, ccnt, out);
}

// Round 4
// 173.525 us; speedup vs baseline: 6.3247x; 1.4376x over previous
//
#include <hip/hip_runtime.h>

// HybridGeometryFeatures: B=2, N=12288, K=16 NN (excl self) + covariance eig features.
// knn: per (query, chunk of 768) branchless top-8 of quantized keys
//      key = (float_bits(d2) & 0xFFFFFC00) | relidx  -> writes 8 u16 global indices.
// feat: wave-per-query; lane holds 2 of the 128 candidate indices, recomputes
//       EXACT f32 d2 (bit-identical expr), merges via 17x extract-min on
//       u64 (d2bits<<32|idx) keys (exact selection, smallest-index tie-break),
//       then shuffle-reduced centroid/cov + f64 eigensolve + features.
// ws: xs/ys/zs (295KB) | cidx u16 [NQ][128] (6.3MB). Total 6.6MB.

#define NPTS 12288
#define NBATCH 2
#define NQ (NPTS * NBATCH)
#define KNN 16
#define NCH 16
#define CHSZ (NPTS / NCH) // 768
#define MKEEP 8
#define QBLK (NQ / 256) // 96

typedef unsigned long long u64;
typedef unsigned short u16;
typedef unsigned int u32;

#define SWAPU(a, b) { u32 _lo = min(a, b); u32 _hi = max(a, b); a = _lo; b = _hi; }
#define DIST(dst, px, py, pz) { float _dx = Qx - (px); float _dy = Qy - (py); float _dz = Qz - (pz); \
                                dst = fmaf(_dz, _dz, fmaf(_dy, _dy, _dx * _dx)); }
#define KEY(kk, dd, rel) { kk = (__float_as_uint(dd) & 0xFFFFFC00u) | (u32)(rel); }

__device__ __forceinline__ u64 shfl_xor_u64(u64 v, int mask) {
  u32 lo = (u32)v, hi = (u32)(v >> 32);
  lo = (u32)__shfl_xor((int)lo, mask);
  hi = (u32)__shfl_xor((int)hi, mask);
  return ((u64)hi << 32) | lo;
}

__global__ __launch_bounds__(256) void pack_kernel(const float* __restrict__ xyz,
                                                   float* __restrict__ xs,
                                                   float* __restrict__ ys,
                                                   float* __restrict__ zs) {
  int i = blockIdx.x * 256 + threadIdx.x;
  if (i < NQ) {
    xs[i] = xyz[3 * i + 0];
    ys[i] = xyz[3 * i + 1];
    zs[i] = xyz[3 * i + 2];
  }
}

// One thread = one query x one chunk of 768 candidates. Branchless top-8
// quantized keys; epilogue writes the 8 indices as u16 (16B coalesced).
__global__ __launch_bounds__(256) void knn_kernel(const float* __restrict__ xs,
                                                  const float* __restrict__ ys,
                                                  const float* __restrict__ zs,
                                                  u16* __restrict__ cidx) {
  int bid = blockIdx.x;
  int qb = bid % QBLK;
  int ch = bid / QBLK;
  int q = qb * 256 + threadIdx.x;
  int b = q / NPTS; // uniform per block
  int base = b * NPTS + ch * CHSZ;

  __shared__ __align__(16) float lx[CHSZ + 8];
  __shared__ __align__(16) float ly[CHSZ + 8];
  __shared__ __align__(16) float lz[CHSZ + 8];
  {
    float4* sx = (float4*)lx; float4* sy = (float4*)ly; float4* sz = (float4*)lz;
    const float4* gx = (const float4*)(xs + base);
    const float4* gy = (const float4*)(ys + base);
    const float4* gz = (const float4*)(zs + base);
    if (threadIdx.x < CHSZ / 4) {
      sx[threadIdx.x] = gx[threadIdx.x];
      sy[threadIdx.x] = gy[threadIdx.x];
      sz[threadIdx.x] = gz[threadIdx.x];
    }
  }
  __syncthreads();

  float Qx = xs[q], Qy = ys[q], Qz = zs[q];

  u32 r0 = ~0u, r1 = ~0u, r2 = ~0u, r3 = ~0u, r4 = ~0u, r5 = ~0u, r6 = ~0u, r7 = ~0u;
  const float4* lx4 = (const float4*)lx;
  const float4* ly4 = (const float4*)ly;
  const float4* lz4 = (const float4*)lz;

  // prime double buffer with batch 0
  float4 ax0 = lx4[0], ax1 = lx4[1];
  float4 ay0 = ly4[0], ay1 = ly4[1];
  float4 az0 = lz4[0], az1 = lz4[1];

#pragma unroll 1
  for (int c0 = 0; c0 < CHSZ; c0 += 8) {
    // prefetch next batch (pad allows overread on last iter)
    int ni = (c0 >> 2) + 2;
    float4 nx0 = lx4[ni], nx1 = lx4[ni + 1];
    float4 ny0 = ly4[ni], ny1 = ly4[ni + 1];
    float4 nz0 = lz4[ni], nz1 = lz4[ni + 1];

    float e0, e1, e2, e3, e4, e5, e6, e7;
    DIST(e0, ax0.x, ay0.x, az0.x); DIST(e1, ax0.y, ay0.y, az0.y);
    DIST(e2, ax0.z, ay0.z, az0.z); DIST(e3, ax0.w, ay0.w, az0.w);
    DIST(e4, ax1.x, ay1.x, az1.x); DIST(e5, ax1.y, ay1.y, az1.y);
    DIST(e6, ax1.z, ay1.z, az1.z); DIST(e7, ax1.w, ay1.w, az1.w);
    u32 d0, d1, d2, d3, d4, d5, d6, d7;
    KEY(d0, e0, c0 + 0); KEY(d1, e1, c0 + 1); KEY(d2, e2, c0 + 2); KEY(d3, e3, c0 + 3);
    KEY(d4, e4, c0 + 4); KEY(d5, e5, c0 + 5); KEY(d6, e6, c0 + 6); KEY(d7, e7, c0 + 7);
    // Batcher sort-8 ascending (19 CEs)
    SWAPU(d0, d1) SWAPU(d2, d3) SWAPU(d4, d5) SWAPU(d6, d7)
    SWAPU(d0, d2) SWAPU(d1, d3) SWAPU(d4, d6) SWAPU(d5, d7)
    SWAPU(d1, d2) SWAPU(d5, d6)
    SWAPU(d0, d4) SWAPU(d1, d5) SWAPU(d2, d6) SWAPU(d3, d7)
    SWAPU(d2, d4) SWAPU(d3, d5)
    SWAPU(d1, d2) SWAPU(d3, d4) SWAPU(d5, d6)
    // keep lowest-8 of (run, batch): cross-min -> bitonic sort-8 (12 CEs)
    u32 m0 = min(r0, d7), m1 = min(r1, d6), m2 = min(r2, d5), m3 = min(r3, d4);
    u32 m4 = min(r4, d3), m5 = min(r5, d2), m6 = min(r6, d1), m7 = min(r7, d0);
    SWAPU(m0, m4) SWAPU(m1, m5) SWAPU(m2, m6) SWAPU(m3, m7)
    SWAPU(m0, m2) SWAPU(m1, m3) SWAPU(m4, m6) SWAPU(m5, m7)
    SWAPU(m0, m1) SWAPU(m2, m3) SWAPU(m4, m5) SWAPU(m6, m7)
    r0 = m0; r1 = m1; r2 = m2; r3 = m3; r4 = m4; r5 = m5; r6 = m6; r7 = m7;

    ax0 = nx0; ax1 = nx1; ay0 = ny0; ay1 = ny1; az0 = nz0; az1 = nz1;
  }

  // epilogue: strip to global-in-batch indices, pack 8 x u16 = 16B store
  u32 cb = (u32)(ch * CHSZ);
  uint4 w;
  w.x = (cb + (r0 & 1023u)) | ((cb + (r1 & 1023u)) << 16);
  w.y = (cb + (r2 & 1023u)) | ((cb + (r3 & 1023u)) << 16);
  w.z = (cb + (r4 & 1023u)) | ((cb + (r5 & 1023u)) << 16);
  w.w = (cb + (r6 & 1023u)) | ((cb + (r7 & 1023u)) << 16);
  *(uint4*)(cidx + (size_t)q * (NCH * MKEEP) + ch * MKEEP) = w;
}

// One wave per query: lane holds 2 candidate indices; exact f32 d2 recompute;
// 17x extract-min on u64 (d2bits<<32|idx); gather + shuffle-reduce + eigensolve.
__global__ __launch_bounds__(256) void feat_kernel(const float* __restrict__ xs,
                                                   const float* __restrict__ ys,
                                                   const float* __restrict__ zs,
                                                   const float* __restrict__ normals,
                                                   const u16* __restrict__ cidx,
                                                   float* __restrict__ out) {
  int wid = threadIdx.x >> 6;
  int lane = threadIdx.x & 63;
  int t = blockIdx.x * 4 + wid; // query 0..NQ
  int b = t / NPTS;
  int qi = t - b * NPTS;
  int bbase = b * NPTS;

  float Qx = xs[t], Qy = ys[t], Qz = zs[t];

  // lane's two candidates (one u32 load = 2 u16, fully coalesced)
  u32 pair = ((const u32*)(cidx + (size_t)t * (NCH * MKEEP)))[lane];
  int ia = (int)(pair & 0xFFFFu);
  int ib = (int)(pair >> 16);
  float dA, dB;
  DIST(dA, xs[bbase + ia], ys[bbase + ia], zs[bbase + ia]);
  DIST(dB, xs[bbase + ib], ys[bbase + ib], zs[bbase + ib]);
  u64 kA = ((u64)__float_as_uint(dA) << 32) | (u32)ia;
  u64 kB = ((u64)__float_as_uint(dB) << 32) | (u32)ib;
  u64 k0 = kA < kB ? kA : kB;
  u64 k1 = kA < kB ? kB : kA;

  u32 myidx = 0;
  int rank = 0;
#pragma unroll
  for (int r = 0; r < KNN + 1; ++r) {
    u64 m = k0;
#pragma unroll
    for (int msk = 1; msk <= 32; msk <<= 1) {
      u64 o = shfl_xor_u64(m, msk);
      m = o < m ? o : m;
    }
    u64 bal = __ballot(k0 == m);
    int src = __ffsll((unsigned long long)bal) - 1;
    int gidx = (int)(m & 0xFFFFu);
    bool win = (lane == src);
    k0 = win ? k1 : k0;
    k1 = win ? ~0ULL : k1;
    bool nonself = (gidx != qi);
    if ((lane == rank) && nonself) myidx = (u32)gidx;
    rank += nonself ? 1 : 0;
  }

  // gather (lanes >=16 load index 0 harmlessly)
  float px = xs[bbase + (int)myidx];
  float py = ys[bbase + (int)myidx];
  float pz = zs[bbase + (int)myidx];

  // centroid over lanes 0-15 (xor masks 1,2,4,8 stay within each 16-group)
  float sx = px, sy = py, sz = pz;
  sx += __shfl_xor(sx, 1); sy += __shfl_xor(sy, 1); sz += __shfl_xor(sz, 1);
  sx += __shfl_xor(sx, 2); sy += __shfl_xor(sy, 2); sz += __shfl_xor(sz, 2);
  sx += __shfl_xor(sx, 4); sy += __shfl_xor(sy, 4); sz += __shfl_xor(sz, 4);
  sx += __shfl_xor(sx, 8); sy += __shfl_xor(sy, 8); sz += __shfl_xor(sz, 8);
  const float invK = 1.0f / 16.0f;
  float cx = sx * invK, cy = sy * invK, cz = sz * invK;

  float dx = px - cx, dy = py - cy, dz = pz - cz;
  float c00 = dx * dx, c01 = dx * dy, c02 = dx * dz;
  float c11 = dy * dy, c12 = dy * dz, c22 = dz * dz;
#pragma unroll
  for (int m = 1; m <= 8; m <<= 1) {
    c00 += __shfl_xor(c00, m); c01 += __shfl_xor(c01, m); c02 += __shfl_xor(c02, m);
    c11 += __shfl_xor(c11, m); c12 += __shfl_xor(c12, m); c22 += __shfl_xor(c22, m);
  }
  const float inv15 = 1.0f / 15.0f;
  c00 *= inv15; c01 *= inv15; c02 *= inv15;
  c11 *= inv15; c12 *= inv15; c22 *= inv15;

  // f64 analytic eigensolve (smallest eigenvalue) — proven round-2 path.
  double a00 = c00, a01 = c01, a02 = c02, a11 = c11, a12 = c12, a22 = c22;
  double tr = a00 + a11 + a22;
  double qm = tr * (1.0 / 3.0);
  double p1 = a01 * a01 + a02 * a02 + a12 * a12;
  double b00 = a00 - qm, b11 = a11 - qm, b22 = a22 - qm;
  double p2 = b00 * b00 + b11 * b11 + b22 * b22 + 2.0 * p1;
  double lmin = qm;
  if (p2 > 0.0) {
    double p = sqrt(p2 * (1.0 / 6.0));
    double ip = 1.0 / p;
    double q00 = b00 * ip, q01 = a01 * ip, q02 = a02 * ip;
    double q11 = b11 * ip, q12 = a12 * ip, q22 = b22 * ip;
    double det = q00 * (q11 * q22 - q12 * q12) - q01 * (q01 * q22 - q12 * q02) +
                 q02 * (q01 * q12 - q11 * q02);
    double r = 0.5 * det;
    r = r < -1.0 ? -1.0 : (r > 1.0 ? 1.0 : r);
    double phi = acos(r) * (1.0 / 3.0);
    lmin = qm + 2.0 * p * cos(phi + 2.0943951023931953);
  }

  // eigenvector: cross products of rows of (A - lmin I), pick largest.
  double m00 = a00 - lmin, m11 = a11 - lmin, m22 = a22 - lmin;
  double v0x = a01 * a12 - a02 * m11;
  double v0y = a02 * a01 - m00 * a12;
  double v0z = m00 * m11 - a01 * a01;
  double v1x = a01 * m22 - a02 * a12;
  double v1y = a02 * a02 - m00 * m22;
  double v1z = m00 * a12 - a01 * a02;
  double v2x = m11 * m22 - a12 * a12;
  double v2y = a12 * a02 - a01 * m22;
  double v2z = a01 * a12 - m11 * a02;
  double n0 = v0x * v0x + v0y * v0y + v0z * v0z;
  double n1 = v1x * v1x + v1y * v1y + v1z * v1z;
  double n2 = v2x * v2x + v2y * v2y + v2z * v2z;
  double vx, vy, vz, nn;
  if (n0 >= n1 && n0 >= n2) { vx = v0x; vy = v0y; vz = v0z; nn = n0; }
  else if (n1 >= n2)        { vx = v1x; vy = v1y; vz = v1z; nn = n1; }
  else                      { vx = v2x; vy = v2y; vz = v2z; nn = n2; }
  if (nn < 1e-60) { vx = 0.0; vy = 0.0; vz = 1.0; nn = 1.0; }
  double inn = 1.0 / sqrt(nn);
  float vxf = (float)(vx * inn), vyf = (float)(vy * inn), vzf = (float)(vz * inn);

  // roughness: mean |centered . v| over lanes 0-15
  float s = fabsf(dx * vxf + dy * vyf + dz * vzf);
  s += __shfl_xor(s, 1);
  s += __shfl_xor(s, 2);
  s += __shfl_xor(s, 4);
  s += __shfl_xor(s, 8);

  if (lane == 0) {
    float nrx = normals[3 * (size_t)t + 0];
    float nry = normals[3 * (size_t)t + 1];
    float nrz = normals[3 * (size_t)t + 2];
    float dot = vxf * nrx + vyf * nry + vzf * nrz;
    float cons = fabsf(dot);
    float trf = c00 + c11 + c22;
    float curv = (float)lmin / fmaxf(trf, 1e-8f);
    float* o = out + (size_t)t * 6;
    o[0] = cons;
    o[1] = nrx;
    o[2] = nry;
    o[3] = nrz;
    o[4] = curv;
    o[5] = s * invK;
  }
}

extern "C" void kernel_launch(void* const* d_in, const int* in_sizes, int n_in,
                              void* d_out, int out_size, void* d_ws, size_t ws_size,
                              hipStream_t stream) {
  const float* xyz = (const float*)d_in[0];
  const float* normals = (const float*)d_in[1];
  float* out = (float*)d_out;

  float* xs = (float*)d_ws;
  float* ys = xs + NQ;
  float* zs = ys + NQ;
  u16* cidx = (u16*)(zs + NQ); // NQ*128 u16 = 6.3MB

  pack_kernel<<<NQ / 256, 256, 0, stream>>>(xyz, xs, ys, zs);
  knn_kernel<<<QBLK * NCH, 256, 0, stream>>>(xs, ys, zs, cidx);
  feat_kernel<<<NQ / 4, 256, 0, stream>>>(xs, ys, zs, normals, cidx, out);
}

// Round 5
// 149.228 us; speedup vs baseline: 7.3544x; 1.1628x over previous
//
#include <hip/hip_runtime.h>

// HybridGeometryFeatures: B=2, N=12288, K=16 NN (excl self) + covariance eig features.
// knn: per (query, chunk of 768) branchless top-8 of quantized keys on
//      s = (|q|^2+|p|^2) - 2 q.p  (1 add + 3 fma)  -> 8 u16 global indices.
// feat: wave-per-query; exact f32 d2 recompute (difference form, bench-proven),
//       full bitonic sort-128 of u64 (d2bits<<32|idx) keys (2 elems/lane),
//       ballot-prefix compaction of first 16 non-self ranks, shuffle-reduced
//       centroid/cov + f64 eigensolve + features.
// ws: xs/ys/zs/ps (393KB) | cidx u16 [NQ][128] (6.3MB). Total 6.7MB.

#define NPTS 12288
#define NBATCH 2
#define NQ (NPTS * NBATCH)
#define KNN 16
#define NCH 16
#define CHSZ (NPTS / NCH) // 768
#define MKEEP 8
#define QBLK (NQ / 256) // 96

typedef unsigned long long u64;
typedef unsigned short u16;
typedef unsigned int u32;

#define SWAPU(a, b) { u32 _lo = min(a, b); u32 _hi = max(a, b); a = _lo; b = _hi; }
#define DIST(dst, px, py, pz) { float _dx = Qx - (px); float _dy = Qy - (py); float _dz = Qz - (pz); \
                                dst = fmaf(_dz, _dz, fmaf(_dy, _dy, _dx * _dx)); }
#define KEY(kk, dd, rel) { kk = (__float_as_uint(dd) & 0xFFFFFC00u) | (u32)(rel); }

__device__ __forceinline__ u64 shfl_xor_u64(u64 v, int mask) {
  u32 lo = (u32)v, hi = (u32)(v >> 32);
  lo = (u32)__shfl_xor((int)lo, mask);
  hi = (u32)__shfl_xor((int)hi, mask);
  return ((u64)hi << 32) | lo;
}

__global__ __launch_bounds__(256) void pack_kernel(const float* __restrict__ xyz,
                                                   float* __restrict__ xs,
                                                   float* __restrict__ ys,
                                                   float* __restrict__ zs,
                                                   float* __restrict__ ps) {
  int i = blockIdx.x * 256 + threadIdx.x;
  if (i < NQ) {
    float x = xyz[3 * i + 0], y = xyz[3 * i + 1], z = xyz[3 * i + 2];
    xs[i] = x; ys[i] = y; zs[i] = z;
    ps[i] = fmaf(z, z, fmaf(y, y, x * x));
  }
}

// One thread = one query x one chunk of 768 candidates. Branchless top-8
// quantized keys on the expansion-form rank value s.
__global__ __launch_bounds__(256) void knn_kernel(const float* __restrict__ xs,
                                                  const float* __restrict__ ys,
                                                  const float* __restrict__ zs,
                                                  const float* __restrict__ ps,
                                                  u16* __restrict__ cidx) {
  int bid = blockIdx.x;
  int qb = bid % QBLK;
  int ch = bid / QBLK;
  int q = qb * 256 + threadIdx.x;
  int b = q / NPTS; // uniform per block
  int base = b * NPTS + ch * CHSZ;

  __shared__ __align__(16) float lx[CHSZ + 8];
  __shared__ __align__(16) float ly[CHSZ + 8];
  __shared__ __align__(16) float lz[CHSZ + 8];
  __shared__ __align__(16) float lp[CHSZ + 8];
  {
    float4* sx = (float4*)lx; float4* sy = (float4*)ly;
    float4* sz = (float4*)lz; float4* sp = (float4*)lp;
    const float4* gx = (const float4*)(xs + base);
    const float4* gy = (const float4*)(ys + base);
    const float4* gz = (const float4*)(zs + base);
    const float4* gp = (const float4*)(ps + base);
    if (threadIdx.x < CHSZ / 4) {
      sx[threadIdx.x] = gx[threadIdx.x];
      sy[threadIdx.x] = gy[threadIdx.x];
      sz[threadIdx.x] = gz[threadIdx.x];
      sp[threadIdx.x] = gp[threadIdx.x];
    }
  }
  __syncthreads();

  float Qx = xs[q], Qy = ys[q], Qz = zs[q];
  float qq = fmaf(Qz, Qz, fmaf(Qy, Qy, Qx * Qx));
  float m2x = -2.0f * Qx, m2y = -2.0f * Qy, m2z = -2.0f * Qz;

  u32 r0 = ~0u, r1 = ~0u, r2 = ~0u, r3 = ~0u, r4 = ~0u, r5 = ~0u, r6 = ~0u, r7 = ~0u;
  const float4* lx4 = (const float4*)lx;
  const float4* ly4 = (const float4*)ly;
  const float4* lz4 = (const float4*)lz;
  const float4* lp4 = (const float4*)lp;

#define SVAL(dst, px, py, pz, pp) dst = fmaf(m2x, (px), fmaf(m2y, (py), fmaf(m2z, (pz), qq + (pp))));

#pragma unroll 2
  for (int c0 = 0; c0 < CHSZ; c0 += 8) {
    int i4 = c0 >> 2;
    float4 xA = lx4[i4], xB = lx4[i4 + 1];
    float4 yA = ly4[i4], yB = ly4[i4 + 1];
    float4 zA = lz4[i4], zB = lz4[i4 + 1];
    float4 pA = lp4[i4], pB = lp4[i4 + 1];
    float e0, e1, e2, e3, e4, e5, e6, e7;
    SVAL(e0, xA.x, yA.x, zA.x, pA.x) SVAL(e1, xA.y, yA.y, zA.y, pA.y)
    SVAL(e2, xA.z, yA.z, zA.z, pA.z) SVAL(e3, xA.w, yA.w, zA.w, pA.w)
    SVAL(e4, xB.x, yB.x, zB.x, pB.x) SVAL(e5, xB.y, yB.y, zB.y, pB.y)
    SVAL(e6, xB.z, yB.z, zB.z, pB.z) SVAL(e7, xB.w, yB.w, zB.w, pB.w)
    u32 d0, d1, d2, d3, d4, d5, d6, d7;
    KEY(d0, e0, c0 + 0); KEY(d1, e1, c0 + 1); KEY(d2, e2, c0 + 2); KEY(d3, e3, c0 + 3);
    KEY(d4, e4, c0 + 4); KEY(d5, e5, c0 + 5); KEY(d6, e6, c0 + 6); KEY(d7, e7, c0 + 7);
    // Batcher sort-8 ascending (19 CEs)
    SWAPU(d0, d1) SWAPU(d2, d3) SWAPU(d4, d5) SWAPU(d6, d7)
    SWAPU(d0, d2) SWAPU(d1, d3) SWAPU(d4, d6) SWAPU(d5, d7)
    SWAPU(d1, d2) SWAPU(d5, d6)
    SWAPU(d0, d4) SWAPU(d1, d5) SWAPU(d2, d6) SWAPU(d3, d7)
    SWAPU(d2, d4) SWAPU(d3, d5)
    SWAPU(d1, d2) SWAPU(d3, d4) SWAPU(d5, d6)
    // keep lowest-8 of (run, batch): cross-min -> bitonic resort (12 CEs)
    u32 m0 = min(r0, d7), m1 = min(r1, d6), m2 = min(r2, d5), m3 = min(r3, d4);
    u32 m4 = min(r4, d3), m5 = min(r5, d2), m6 = min(r6, d1), m7 = min(r7, d0);
    SWAPU(m0, m4) SWAPU(m1, m5) SWAPU(m2, m6) SWAPU(m3, m7)
    SWAPU(m0, m2) SWAPU(m1, m3) SWAPU(m4, m6) SWAPU(m5, m7)
    SWAPU(m0, m1) SWAPU(m2, m3) SWAPU(m4, m5) SWAPU(m6, m7)
    r0 = m0; r1 = m1; r2 = m2; r3 = m3; r4 = m4; r5 = m5; r6 = m6; r7 = m7;
  }

  // epilogue: strip to global-in-batch indices, pack 8 x u16 = 16B store
  u32 cb = (u32)(ch * CHSZ);
  uint4 w;
  w.x = (cb + (r0 & 1023u)) | ((cb + (r1 & 1023u)) << 16);
  w.y = (cb + (r2 & 1023u)) | ((cb + (r3 & 1023u)) << 16);
  w.z = (cb + (r4 & 1023u)) | ((cb + (r5 & 1023u)) << 16);
  w.w = (cb + (r6 & 1023u)) | ((cb + (r7 & 1023u)) << 16);
  *(uint4*)(cidx + (size_t)q * (NCH * MKEEP) + ch * MKEEP) = w;
}

// One wave per query: exact d2 recompute for lane's 2 candidates; full bitonic
// sort-128 of u64 keys (element i = 2*lane+slot); first-16-non-self compaction;
// covariance + f64 eigensolve + features (all lanes replicated, lane 0 writes).
__global__ __launch_bounds__(256) void feat_kernel(const float* __restrict__ xs,
                                                   const float* __restrict__ ys,
                                                   const float* __restrict__ zs,
                                                   const float* __restrict__ normals,
                                                   const u16* __restrict__ cidx,
                                                   float* __restrict__ out) {
  __shared__ u32 selidx[4][16];
  int wid = threadIdx.x >> 6;
  int lane = threadIdx.x & 63;
  int t = blockIdx.x * 4 + wid; // query 0..NQ
  int b = t / NPTS;
  int qi = t - b * NPTS;
  int bbase = b * NPTS;

  float Qx = xs[t], Qy = ys[t], Qz = zs[t];

  // lane's two candidates (one u32 load = 2 u16, coalesced)
  u32 pair = ((const u32*)(cidx + (size_t)t * (NCH * MKEEP)))[lane];
  int ia = (int)(pair & 0xFFFFu);
  int ib = (int)(pair >> 16);
  float dA, dB;
  DIST(dA, xs[bbase + ia], ys[bbase + ia], zs[bbase + ia]);
  DIST(dB, xs[bbase + ib], ys[bbase + ib], zs[bbase + ib]);
  u64 e0 = ((u64)__float_as_uint(dA) << 32) | (u32)ia;
  u64 e1 = ((u64)__float_as_uint(dB) << 32) | (u32)ib;

  // bitonic sort of 128 elements ascending; element index i = 2*lane + slot.
#pragma unroll
  for (int k = 2; k <= 128; k <<= 1) {
#pragma unroll
    for (int j = k >> 1; j > 0; j >>= 1) {
      if (j >= 2) {
        int h = j >> 1; // lane-xor distance (1..32)
        u64 p0 = shfl_xor_u64(e0, h);
        u64 p1 = shfl_xor_u64(e1, h);
        bool wantmin = (((lane & h) == 0) == (((2 * lane) & k) == 0));
        e0 = wantmin ? (p0 < e0 ? p0 : e0) : (p0 > e0 ? p0 : e0);
        e1 = wantmin ? (p1 < e1 ? p1 : e1) : (p1 > e1 ? p1 : e1);
      } else {
        bool asc = (((2 * lane) & k) == 0);
        u64 mn = e0 < e1 ? e0 : e1;
        u64 mx = e0 < e1 ? e1 : e0;
        e0 = asc ? mn : mx;
        e1 = asc ? mx : mn;
      }
    }
  }

  // compact first 16 non-self ranks into LDS (rank of slot s at lane l = 2l+s)
  u32 i0 = (u32)e0 & 0xFFFFu;
  u32 i1 = (u32)e1 & 0xFFFFu;
  bool f0 = (int)i0 != qi;
  bool f1 = (int)i1 != qi;
  u64 b0 = __ballot(f0);
  u64 b1 = __ballot(f1);
  u64 lm = lane ? (~0ull >> (64 - lane)) : 0ull;
  int pre0 = __popcll(b0 & lm) + __popcll(b1 & lm);
  int pre1 = pre0 + (f0 ? 1 : 0);
  if (f0 && pre0 < KNN) selidx[wid][pre0] = i0;
  if (f1 && pre1 < KNN) selidx[wid][pre1] = i1;
  __syncthreads();

  int nidx = selidx[wid][lane & 15];
  float px = xs[bbase + nidx];
  float py = ys[bbase + nidx];
  float pz = zs[bbase + nidx];

  // centroid over each 16-lane group (all groups hold identical data)
  float sx = px, sy = py, sz = pz;
  sx += __shfl_xor(sx, 1); sy += __shfl_xor(sy, 1); sz += __shfl_xor(sz, 1);
  sx += __shfl_xor(sx, 2); sy += __shfl_xor(sy, 2); sz += __shfl_xor(sz, 2);
  sx += __shfl_xor(sx, 4); sy += __shfl_xor(sy, 4); sz += __shfl_xor(sz, 4);
  sx += __shfl_xor(sx, 8); sy += __shfl_xor(sy, 8); sz += __shfl_xor(sz, 8);
  const float invK = 1.0f / 16.0f;
  float cx = sx * invK, cy = sy * invK, cz = sz * invK;

  float dx = px - cx, dy = py - cy, dz = pz - cz;
  float c00 = dx * dx, c01 = dx * dy, c02 = dx * dz;
  float c11 = dy * dy, c12 = dy * dz, c22 = dz * dz;
#pragma unroll
  for (int m = 1; m <= 8; m <<= 1) {
    c00 += __shfl_xor(c00, m); c01 += __shfl_xor(c01, m); c02 += __shfl_xor(c02, m);
    c11 += __shfl_xor(c11, m); c12 += __shfl_xor(c12, m); c22 += __shfl_xor(c22, m);
  }
  const float inv15 = 1.0f / 15.0f;
  c00 *= inv15; c01 *= inv15; c02 *= inv15;
  c11 *= inv15; c12 *= inv15; c22 *= inv15;

  // f64 analytic eigensolve (smallest eigenvalue) — proven path.
  double a00 = c00, a01 = c01, a02 = c02, a11 = c11, a12 = c12, a22 = c22;
  double tr = a00 + a11 + a22;
  double qm = tr * (1.0 / 3.0);
  double p1 = a01 * a01 + a02 * a02 + a12 * a12;
  double b00 = a00 - qm, b11 = a11 - qm, b22 = a22 - qm;
  double p2 = b00 * b00 + b11 * b11 + b22 * b22 + 2.0 * p1;
  double lmin = qm;
  if (p2 > 0.0) {
    double p = sqrt(p2 * (1.0 / 6.0));
    double ip = 1.0 / p;
    double q00 = b00 * ip, q01 = a01 * ip, q02 = a02 * ip;
    double q11 = b11 * ip, q12 = a12 * ip, q22 = b22 * ip;
    double det = q00 * (q11 * q22 - q12 * q12) - q01 * (q01 * q22 - q12 * q02) +
                 q02 * (q01 * q12 - q11 * q02);
    double r = 0.5 * det;
    r = r < -1.0 ? -1.0 : (r > 1.0 ? 1.0 : r);
    double phi = acos(r) * (1.0 / 3.0);
    lmin = qm + 2.0 * p * cos(phi + 2.0943951023931953);
  }

  // eigenvector: cross products of rows of (A - lmin I), pick largest.
  double m00 = a00 - lmin, m11 = a11 - lmin, m22 = a22 - lmin;
  double v0x = a01 * a12 - a02 * m11;
  double v0y = a02 * a01 - m00 * a12;
  double v0z = m00 * m11 - a01 * a01;
  double v1x = a01 * m22 - a02 * a12;
  double v1y = a02 * a02 - m00 * m22;
  double v1z = m00 * a12 - a01 * a02;
  double v2x = m11 * m22 - a12 * a12;
  double v2y = a12 * a02 - a01 * m22;
  double v2z = a01 * a12 - m11 * a02;
  double n0 = v0x * v0x + v0y * v0y + v0z * v0z;
  double n1 = v1x * v1x + v1y * v1y + v1z * v1z;
  double n2 = v2x * v2x + v2y * v2y + v2z * v2z;
  double vx, vy, vz, nn;
  if (n0 >= n1 && n0 >= n2) { vx = v0x; vy = v0y; vz = v0z; nn = n0; }
  else if (n1 >= n2)        { vx = v1x; vy = v1y; vz = v1z; nn = n1; }
  else                      { vx = v2x; vy = v2y; vz = v2z; nn = n2; }
  if (nn < 1e-60) { vx = 0.0; vy = 0.0; vz = 1.0; nn = 1.0; }
  double inn = 1.0 / sqrt(nn);
  float vxf = (float)(vx * inn), vyf = (float)(vy * inn), vzf = (float)(vz * inn);

  // roughness: mean |centered . v| over the 16-lane group
  float s = fabsf(dx * vxf + dy * vyf + dz * vzf);
  s += __shfl_xor(s, 1);
  s += __shfl_xor(s, 2);
  s += __shfl_xor(s, 4);
  s += __shfl_xor(s, 8);

  if (lane == 0) {
    float nrx = normals[3 * (size_t)t + 0];
    float nry = normals[3 * (size_t)t + 1];
    float nrz = normals[3 * (size_t)t + 2];
    float dot = vxf * nrx + vyf * nry + vzf * nrz;
    float cons = fabsf(dot);
    float trf = c00 + c11 + c22;
    float curv = (float)lmin / fmaxf(trf, 1e-8f);
    float* o = out + (size_t)t * 6;
    o[0] = cons;
    o[1] = nrx;
    o[2] = nry;
    o[3] = nrz;
    o[4] = curv;
    o[5] = s * invK;
  }
}

extern "C" void kernel_launch(void* const* d_in, const int* in_sizes, int n_in,
                              void* d_out, int out_size, void* d_ws, size_t ws_size,
                              hipStream_t stream) {
  const float* xyz = (const float*)d_in[0];
  const float* normals = (const float*)d_in[1];
  float* out = (float*)d_out;

  float* xs = (float*)d_ws;
  float* ys = xs + NQ;
  float* zs = ys + NQ;
  float* ps = zs + NQ;
  u16* cidx = (u16*)(ps + NQ); // NQ*128 u16 = 6.3MB

  pack_kernel<<<NQ / 256, 256, 0, stream>>>(xyz, xs, ys, zs, ps);
  knn_kernel<<<QBLK * NCH, 256, 0, stream>>>(xs, ys, zs, ps, cidx);
  feat_kernel<<<NQ / 4, 256, 0, stream>>>(xs, ys, zs, normals, cidx, out);
}